// Round 13
// baseline (122.296 us; speedup 1.0000x reference)
//
#include <hip/hip_runtime.h>

#define THREADS 256
#define IPB 4   // images per block; grid = 8192/4 = 2048 = 256 CU x 8 (one round)

typedef _Float16 f16;
typedef _Float16 f16x2 __attribute__((ext_vector_type(2)));
typedef _Float16 f16x4 __attribute__((ext_vector_type(4)));
typedef _Float16 f16x8 __attribute__((ext_vector_type(8)));
typedef float f32x2 __attribute__((ext_vector_type(2)));
typedef float f32x4 __attribute__((ext_vector_type(4)));
typedef float f32x16 __attribute__((ext_vector_type(16)));
typedef unsigned int uint;

__device__ __forceinline__ f16x2 pkrtz(float a, float b) {
    return __builtin_bit_cast(f16x2, __builtin_amdgcn_cvt_pkrtz(a, b));
}
template<int CTRL>
__device__ __forceinline__ float dppmax(float v) {   // fmax with DPP-shuffled lane
    const int i = __builtin_bit_cast(int, v);
    const int s = __builtin_amdgcn_update_dpp(i, i, CTRL, 0xF, 0xF, true);
    return fmaxf(v, __builtin_bit_cast(float, s));
}
// read 8 consecutive f16 window cols from the shifted-pairs image: pairs[c] =
// (xh[c], xh[c+1]) so cols ox..ox+7 = pairs{ox,ox+2,ox+4,ox+6}; every read is
// 4B-aligned for ANY ox.
__device__ __forceinline__ f16x8 ldpairs(const unsigned char* a) {
    const uint* p = (const uint*)a;
    uint4 u;
    u.x = p[0]; u.y = p[2]; u.z = p[4]; u.w = p[6];
    return __builtin_bit_cast(f16x8, u);
}

// p1 (pooled conv1 out): [img][iy 12][ix 12][ic 12] f16.
// R13: ic10 == 1.0 EVERYWHERE (conv1 A-row 10 outputs the constant 1 via the
// bias-slot trick); conv2's w2af carries b2[oc] in its center-tap ic10 slot,
// so conv2's bias rides inside the MFMA K-sum and the epilogue needs no b2.
// ic11 exact zero. XOR swizzle (R11): phys = row*288 + (C ^ ((row&3)<<3)).
#define P1C 24
#define P1R 288
#define P1I 3456   // 4 imgs = 13824 B
// pairs region (row-interleaved): [row 28][imL 2][pair 28] f16x2, 224 B/row.
// Tail [20096,20224) zeroed ONCE (sub 0): padded-window reads overrun past the
// last row; they multiply zero weights but must be FINITE (NaN*0 = NaN).
#define XH  13824
#define SMEM_BYTES 20224

// p2h k-ORDER: k' = pos*20 + m (pos=py*4+px); conv2 epilogue stores aligned
// f16x4 runs; fc1 A-frags packed with the inverse map (k_ref = m*16 + pos).

// d_ws layout ([0,1024) unused):
//   [1024)   w2af   1000 x f16x8  (conv2 A-frags [s][oc*2+hK]; bias in s==12)
//   [17408)  wl1pk  2560 x f16x8  (fc1 A-frags [tile][s][lane], k'-ordered)
__global__ void pack_weights(const float* __restrict__ w1,
                             const float* __restrict__ w2,
                             const float* __restrict__ wl1,
                             const float* __restrict__ b2,
                             unsigned char* __restrict__ ws) {
    f16x8* w2af = (f16x8*)(ws + 1024);
    f16x8* wl1pk = (f16x8*)(ws + 17408);
    const int gid = blockIdx.x * blockDim.x + threadIdx.x;
    const int gsz = gridDim.x * blockDim.x;
    for (int e = gid; e < 1000; e += gsz) {          // conv2 A-frags
        const int s = e / 40, r = e - s * 40;
        const int oc = r >> 1, h = r & 1;
        f16x8 a;
        #pragma unroll
        for (int j = 0; j < 8; ++j) {
            const int ic = h * 8 + j;
            float v = 0.f;
            if (ic < 10) v = w2[(oc * 10 + ic) * 25 + s];
            else if (ic == 10 && s == 12) v = b2[oc];  // bias x p1(ic10)==1.0
            a[j] = (f16)v;
        }
        w2af[e] = a;
    }
    for (int e = gid; e < 2560; e += gsz) {          // fc1 A-frags, k'-ordered
        const int tile = e / 640, rem = e % 640;
        const int s = rem / 64, lane = rem % 64;
        const int m16 = lane & 15, quad = lane >> 4;
        const int hh = tile * 16 + m16;
        f16x8 a;
        #pragma unroll
        for (int j = 0; j < 8; ++j) {
            const int kp = s * 32 + quad * 8 + j;    // k' index
            const int pos = kp / 20, mm = kp - pos * 20;
            a[j] = (f16)(hh < 50 ? wl1[hh * 320 + mm * 16 + pos] : 0.f);
        }
        wl1pk[e] = a;
    }
}

__global__ __launch_bounds__(THREADS, 8)
void lenet_one(const float* __restrict__ x,
               const unsigned char* __restrict__ ws,
               const float* __restrict__ w1, const float* __restrict__ b1,
               const float* __restrict__ bl1,
               const float* __restrict__ wl2, const float* __restrict__ bl2,
               float* __restrict__ out, int batch)
{
    __shared__ __align__(16) unsigned char smem[SMEM_BYTES];
    f16*   p2h = (f16*)smem;             // [img][k' 320 pad 328], aliases p1
    float* h1  = (float*)(smem + 2624);  // [img][50 pad 52],      aliases p1
    float* scr = (float*)(smem + XH);    // fc2 partials (pairs region, dead)

    const f16x8* w2af  = (const f16x8*)(ws + 1024);
    const f16x8* wl1pk = (const f16x8*)(ws + 17408);

    const int tid = threadIdx.x;
    const int lane = tid & 63;
    const int wv_ = tid >> 6;                 // wave id 0..3
    const int n15 = lane & 15;                // A-frag oc / B-frag position
    const int q4  = lane >> 4;                // quad
    const int cM = lane & 31, hK = lane >> 5; // conv2 MFMA roles

    // ---------- conv1 A-fragments, built once from global (registers) --------
    // chunk1: k = wrow*8 + wcol (wrow 0..3, wcol 5..7 zero).
    // chunk2: k<8 -> wrow4; slot (q=1,j=0) carries the BIAS (B supplies 1.0).
    // A-row 10 = constant 1.0 output (only its bias slot set, weight 1.0):
    // p1 ic10 == 1.0 everywhere -> carries conv2's bias through the MFMA.
    f16x8 A1 = {}, A2 = {};
    if (n15 < 10) {
        #pragma unroll
        for (int j = 0; j < 5; ++j) A1[j] = (f16)w1[n15 * 25 + q4 * 5 + j];
        if (q4 == 0) {
            #pragma unroll
            for (int j = 0; j < 5; ++j) A2[j] = (f16)w1[n15 * 25 + 20 + j];
        }
        if (q4 == 1) A2[0] = (f16)b1[n15];
    }
    if (n15 == 10 && q4 == 1) A2[0] = (f16)1.f;   // row10 -> 1.0 everywhere

    // ---------- conv1 via MFMA, two sub-phases of 2 images each --------------
    #pragma unroll 1
    for (int sub = 0; sub < 2; ++sub) {
        // stage x as shifted f16 pairs, row-interleaved across the 2 images.
        if (tid < 112) {
            const int rr = tid >> 2, imL = (tid >> 1) & 1, half = tid & 1;
            const int ig = min(blockIdx.x * IPB + sub * 2 + imL, batch - 1);
            const float* xp = x + (size_t)ig * 784 + rr * 28 + half * 14;
            float v[15];
            #pragma unroll
            for (int t = 0; t < 7; ++t) {
                const f32x2 a = *(const f32x2*)(xp + 2 * t);
                v[2 * t] = a[0]; v[2 * t + 1] = a[1];
            }
            v[14] = half ? 0.f : xp[14];
            uint* pw = (uint*)(smem + XH + rr * 224 + imL * 112) + half * 14;
            #pragma unroll
            for (int t = 0; t < 7; ++t) {
                uint2 w;
                w.x = __builtin_bit_cast(uint, pkrtz(v[2 * t], v[2 * t + 1]));
                w.y = __builtin_bit_cast(uint, pkrtz(v[2 * t + 1], v[2 * t + 2]));
                *(uint2*)(pw + 2 * t) = w;
            }
        } else if (sub == 0 && tid >= 224) {   // finite zero tail, written once
            *(uint*)(smem + XH + 28 * 224 + (tid - 224) * 4) = 0;
        }
        __syncthreads();

        // pool loop: wave = (imL = wv>>1, oxg = wv&1); u = 11..0 fully
        // unrolled -> every LDS address is base + compile-time immediate.
        // B2 rows (2u+4, 2u+5) = quad0's B1 rows of iteration u+2 -> 2-deep
        // named-register history (u=11,10 read direct).
        {
            const int imL = wv_ >> 1, oxg = wv_ & 1;
            const int ox = oxg * 16 + n15;
            const int im = sub * 2 + imL;
            const unsigned char* pb = smem + XH + imL * 112 + ox * 4
                                    + q4 * 224;           // + row offset base
            unsigned char* wbase = smem + im * P1I;
            f16x8 hA0 = {}, hB0 = {}, hA1 = {}, hB1 = {};
            #pragma unroll
            for (int uu = 0; uu < 12; ++uu) {
                const int u = 11 - uu;
                const f16x8 B1a = ldpairs(pb + (2 * u) * 224);
                const f16x8 B1b = ldpairs(pb + (2 * u + 1) * 224);
                f16x8 B2a, B2b;
                if (u >= 10) {   // compile-time branch
                    B2a = ldpairs(pb - q4 * 224 + (2 * u + 4) * 224);
                    B2b = ldpairs(pb - q4 * 224 + (2 * u + 5) * 224);
                } else {
                    B2a = (u & 1) ? hA1 : hA0;
                    B2b = (u & 1) ? hB1 : hB0;
                }
                if (u & 1) { hA1 = B1a; hB1 = B1b; }
                else       { hA0 = B1a; hB0 = B1b; }
                if (q4 == 1) { B2a[0] = (f16)1.f; B2b[0] = (f16)1.f; } // bias
                f32x4 aa = {0.f, 0.f, 0.f, 0.f}, ab = {0.f, 0.f, 0.f, 0.f};
                aa = __builtin_amdgcn_mfma_f32_16x16x32_f16(A1, B1a, aa, 0, 0, 0);
                ab = __builtin_amdgcn_mfma_f32_16x16x32_f16(A1, B1b, ab, 0, 0, 0);
                aa = __builtin_amdgcn_mfma_f32_16x16x32_f16(A2, B2a, aa, 0, 0, 0);
                ab = __builtin_amdgcn_mfma_f32_16x16x32_f16(A2, B2b, ab, 0, 0, 0);
                // pool (rows in-register, cols via DPP xor1) + relu
                float vr[4];
                #pragma unroll
                for (int r = 0; r < 4; ++r) {
                    float v = fmaxf(aa[r], ab[r]);
                    v = dppmax<0xB1>(v);               // lane n <-> n^1
                    vr[r] = fmaxf(v, 0.f);
                }
                if (!(lane & 1) && q4 < 3 && (oxg == 0 || n15 < 8)) {
                    const int px = oxg * 8 + (n15 >> 1);
                    f16x2 o0, o1;
                    o0[0] = (f16)vr[0]; o0[1] = (f16)vr[1];
                    o1[0] = (f16)vr[2]; o1[1] = (f16)vr[3];
                    uint2 w;
                    w.x = __builtin_bit_cast(uint, o0);
                    w.y = __builtin_bit_cast(uint, o1);
                    // XOR-swizzled in-row offset (key = u&3, compile-time)
                    const int Cw = (px * P1C + q4 * 8) ^ ((u & 3) << 3);
                    *(uint2*)(wbase + u * P1R + Cw) = w;
                }
            }
        }
        __syncthreads();
    }

    // ---------- conv2 via mfma_f32_32x32x16_f16 (2 tiles/wave) ---------------
    {
        const int cy = cM >> 3, cx = cM & 7;
        const int afoff = (cM < 20 ? cM : 19) * 2 + hK;
        int rowb[2];
        #pragma unroll
        for (int q = 0; q < 2; ++q) {
            const int t = wv_ * 2 + q, im = t >> 1, h2 = t & 1;
            rowb[q] = im * P1I + (4 * h2 + cy) * P1R;
        }
        const int Cb = cx * P1C + hK * 16;   // in-row byte offset (per-lane)
        f32x16 acc[2];
        #pragma unroll
        for (int q = 0; q < 2; ++q)
            #pragma unroll
            for (int r = 0; r < 16; ++r) acc[q][r] = 0.f;
        #pragma unroll 1
        for (int ky = 0; ky < 5; ++ky) {
            const int Kk = ((cy + ky) & 3) << 3;   // row&3 key (4h2 == 0 mod 4)
            #pragma unroll
            for (int kx = 0; kx < 5; ++kx) {
                const f16x8 a = w2af[(ky * 5 + kx) * 40 + afoff];
                const int Clo = (Cb + kx * P1C) ^ Kk;
                const int Chi = (Cb + kx * P1C + 8) ^ Kk;
                #pragma unroll
                for (int q = 0; q < 2; ++q) {
                    const unsigned char* rp = smem + rowb[q] + ky * P1R;
                    const f16x4 lo = *(const f16x4*)(rp + Clo);
                    const f16x4 hi = *(const f16x4*)(rp + Chi); // ic12-15 junk x 0
                    const f16x8 b = __builtin_shufflevector(lo, hi,
                                                            0, 1, 2, 3, 4, 5, 6, 7);
                    acc[q] = __builtin_amdgcn_mfma_f32_32x32x16_f16(a, b, acc[q],
                                                                    0, 0, 0);
                }
            }
        }
        // all waves done READING p1 before epilogue overwrites it (p2h alias)
        __syncthreads();
        // epilogue: pool via DPP (bias already inside acc), aligned f16x4 store
        #pragma unroll
        for (int q = 0; q < 2; ++q) {
            const int t = wv_ * 2 + q, im = t >> 1, h2 = t & 1;
            const int py = 2 * h2 + (cM >> 4), px = (cM & 7) >> 1;
            f16* base = p2h + im * 328 + (py * 4 + px) * 20 + 4 * hK;
            #pragma unroll
            for (int g = 0; g < 4; ++g) {
                const int m0 = 8 * g + 4 * hK;       // run start channel
                f16x4 vv;
                #pragma unroll
                for (int e = 0; e < 4; ++e) {
                    float v = acc[q][4 * g + e];
                    v = dppmax<0xB1>(v);    // xor1: quad_perm(1,0,3,2)
                    v = dppmax<0x128>(v);   // xor8: row_ror:8
                    vv[e] = (f16)fmaxf(v, 0.f);
                }
                if ((lane & 9) == 0 && m0 < 20)
                    *(f16x4*)(base + 8 * g) = vv;
            }
        }
    }
    __syncthreads();

    // ---------- fc1 via mfma_f32_16x16x32_f16: M=h tile/wave, N=img, K=320 ----
    {
        f32x4 facc = {0.f, 0.f, 0.f, 0.f};
        #pragma unroll 1
        for (int s = 0; s < 10; ++s) {
            const f16x8 a = wl1pk[(wv_ * 10 + s) * 64 + lane];  // coalesced b128
            f16x8 b = {};
            if (n15 < IPB)
                b = *(const f16x8*)(p2h + n15 * 328 + s * 32 + q4 * 8);
            facc = __builtin_amdgcn_mfma_f32_16x16x32_f16(a, b, facc, 0, 0, 0);
        }
        if (n15 < IPB) {
            #pragma unroll
            for (int r = 0; r < 4; ++r) {
                const int h = wv_ * 16 + q4 * 4 + r;
                if (h < 50)
                    h1[n15 * 52 + h] = fmaxf(facc[r] + bl1[h], 0.f);
            }
        }
    }
    __syncthreads();

    // ---------- fc2: 50->10, parallel over 240 threads (6 h-segments) --------
    if (tid < 240) {
        const int o = tid % 10, im = (tid / 10) & 3, seg = tid / 40;
        const int h0 = seg * 9, hE = (seg == 5) ? 50 : h0 + 9;
        float a = 0.f;
        #pragma unroll
        for (int h = h0; h < hE; ++h)
            a += h1[im * 52 + h] * wl2[o * 50 + h];
        scr[tid] = a;
    }
    __syncthreads();
    if (tid < IPB * 10) {
        const int im = tid / 10, o = tid % 10;
        const int imgo = min(blockIdx.x * IPB + im, batch - 1);
        float a = bl2[o];
        #pragma unroll
        for (int seg = 0; seg < 6; ++seg)
            a += scr[seg * 40 + tid];
        out[(size_t)imgo * 10 + o] = a;          // coalesced
    }
}

extern "C" void kernel_launch(void* const* d_in, const int* in_sizes, int n_in,
                              void* d_out, int out_size, void* d_ws, size_t ws_size,
                              hipStream_t stream) {
    const float* x   = (const float*)d_in[0];
    const float* w1  = (const float*)d_in[1];
    const float* b1  = (const float*)d_in[2];
    const float* w2  = (const float*)d_in[3];
    const float* b2  = (const float*)d_in[4];
    const float* wl1 = (const float*)d_in[5];
    const float* bl1 = (const float*)d_in[6];
    const float* wl2 = (const float*)d_in[7];
    const float* bl2 = (const float*)d_in[8];
    float* out = (float*)d_out;
    unsigned char* ws = (unsigned char*)d_ws;

    const int batch = in_sizes[0] / 784;  // 8192
    pack_weights<<<64, 256, 0, stream>>>(w1, w2, wl1, b2, ws);
    const int grid = (batch + IPB - 1) / IPB;
    lenet_one<<<grid, THREADS, 0, stream>>>(x, ws, w1, b1, bl1, wl2, bl2,
                                            out, batch);
}

// Round 14
// 119.814 us; speedup vs baseline: 1.0207x; 1.0207x over previous
//
#include <hip/hip_runtime.h>

#define THREADS 256
#define IPB 4   // images per block; grid = 8192/4 = 2048 = 256 CU x 8 (one round)

typedef _Float16 f16;
typedef _Float16 f16x2 __attribute__((ext_vector_type(2)));
typedef _Float16 f16x4 __attribute__((ext_vector_type(4)));
typedef _Float16 f16x8 __attribute__((ext_vector_type(8)));
typedef float f32x2 __attribute__((ext_vector_type(2)));
typedef float f32x4 __attribute__((ext_vector_type(4)));
typedef float f32x16 __attribute__((ext_vector_type(16)));
typedef unsigned int uint;

__device__ __forceinline__ f16x2 pkrtz(float a, float b) {
    return __builtin_bit_cast(f16x2, __builtin_amdgcn_cvt_pkrtz(a, b));
}
template<int CTRL>
__device__ __forceinline__ float dppmax(float v) {   // fmax with DPP-shuffled lane
    const int i = __builtin_bit_cast(int, v);
    const int s = __builtin_amdgcn_update_dpp(i, i, CTRL, 0xF, 0xF, true);
    return fmaxf(v, __builtin_bit_cast(float, s));
}
// read 8 consecutive f16 window cols from the shifted-pairs image: pairs[c] =
// (xh[c], xh[c+1]) so cols ox..ox+7 = pairs{ox,ox+2,ox+4,ox+6}; every read is
// 4B-aligned for ANY ox.
__device__ __forceinline__ f16x8 ldpairs(const unsigned char* a) {
    const uint* p = (const uint*)a;
    uint4 u;
    u.x = p[0]; u.y = p[2]; u.z = p[4]; u.w = p[6];
    return __builtin_bit_cast(f16x8, u);
}

// p1 (pooled conv1 out): [img][iy 12][ix 12][ic 12] f16.
// ic10 == 1.0 EVERYWHERE (conv1 A-row 10 outputs the constant 1 via the
// bias-slot trick); conv2's w2af carries b2[oc] in its center-tap ic10 slot,
// so conv2's bias rides inside the MFMA K-sum and the epilogue needs no b2.
// ic11 exact zero. XOR swizzle (R11): phys = row*288 + (C ^ ((row&3)<<3)).
#define P1C 24
#define P1R 288
#define P1I 3456   // 4 imgs = 13824 B
// pairs region (row-interleaved): [row 28][imL 2][pair 28] f16x2, 224 B/row.
// Tail [20096,20224) zeroed ONCE (sub 0): padded-window reads overrun past the
// last row; they multiply zero weights but must be FINITE (NaN*0 = NaN).
#define XH  13824
#define SMEM_BYTES 20224

// p2h k-ORDER: k' = pos*20 + m (pos=py*4+px); conv2 epilogue stores aligned
// f16x4 runs; fc1 A-frags packed with the inverse map (k_ref = m*16 + pos).

// d_ws layout ([0,1024) unused):
//   [1024)   w2af   1000 x f16x8  (conv2 A-frags [s][oc*2+hK]; bias in s==12)
//   [17408)  wl1pk  2560 x f16x8  (fc1 A-frags [tile][s][lane], k'-ordered)
__global__ void pack_weights(const float* __restrict__ w1,
                             const float* __restrict__ w2,
                             const float* __restrict__ wl1,
                             const float* __restrict__ b2,
                             unsigned char* __restrict__ ws) {
    f16x8* w2af = (f16x8*)(ws + 1024);
    f16x8* wl1pk = (f16x8*)(ws + 17408);
    const int gid = blockIdx.x * blockDim.x + threadIdx.x;
    const int gsz = gridDim.x * blockDim.x;
    for (int e = gid; e < 1000; e += gsz) {          // conv2 A-frags
        const int s = e / 40, r = e - s * 40;
        const int oc = r >> 1, h = r & 1;
        f16x8 a;
        #pragma unroll
        for (int j = 0; j < 8; ++j) {
            const int ic = h * 8 + j;
            float v = 0.f;
            if (ic < 10) v = w2[(oc * 10 + ic) * 25 + s];
            else if (ic == 10 && s == 12) v = b2[oc];  // bias x p1(ic10)==1.0
            a[j] = (f16)v;
        }
        w2af[e] = a;
    }
    for (int e = gid; e < 2560; e += gsz) {          // fc1 A-frags, k'-ordered
        const int tile = e / 640, rem = e % 640;
        const int s = rem / 64, lane = rem % 64;
        const int m16 = lane & 15, quad = lane >> 4;
        const int hh = tile * 16 + m16;
        f16x8 a;
        #pragma unroll
        for (int j = 0; j < 8; ++j) {
            const int kp = s * 32 + quad * 8 + j;    // k' index
            const int pos = kp / 20, mm = kp - pos * 20;
            a[j] = (f16)(hh < 50 ? wl1[hh * 320 + mm * 16 + pos] : 0.f);
        }
        wl1pk[e] = a;
    }
}

__global__ __launch_bounds__(THREADS, 8)
void lenet_one(const float* __restrict__ x,
               const unsigned char* __restrict__ ws,
               const float* __restrict__ w1, const float* __restrict__ b1,
               const float* __restrict__ bl1,
               const float* __restrict__ wl2, const float* __restrict__ bl2,
               float* __restrict__ out, int batch)
{
    __shared__ __align__(16) unsigned char smem[SMEM_BYTES];
    f16*   p2h = (f16*)smem;             // [img][k' 320 pad 328], aliases p1
    float* h1  = (float*)(smem + 2624);  // [img][50 pad 52],      aliases p1

    const f16x8* w2af  = (const f16x8*)(ws + 1024);
    const f16x8* wl1pk = (const f16x8*)(ws + 17408);

    const int tid = threadIdx.x;
    const int lane = tid & 63;
    const int wv_ = tid >> 6;                 // wave id 0..3
    const int n15 = lane & 15;                // A-frag oc / B-frag position
    const int q4  = lane >> 4;                // quad
    const int cM = lane & 31, hK = lane >> 5; // conv2 MFMA roles

    // ---------- conv1 A-fragments, built once from global (registers) --------
    // chunk1: k = wrow*8 + wcol (wrow 0..3, wcol 5..7 zero).
    // chunk2: k<8 -> wrow4; slot (q=1,j=0) carries the BIAS (B supplies 1.0).
    // A-row 10 = constant 1.0 output (only its bias slot set):
    // p1 ic10 == 1.0 everywhere -> carries conv2's bias through the MFMA.
    f16x8 A1 = {}, A2 = {};
    if (n15 < 10) {
        #pragma unroll
        for (int j = 0; j < 5; ++j) A1[j] = (f16)w1[n15 * 25 + q4 * 5 + j];
        if (q4 == 0) {
            #pragma unroll
            for (int j = 0; j < 5; ++j) A2[j] = (f16)w1[n15 * 25 + 20 + j];
        }
        if (q4 == 1) A2[0] = (f16)b1[n15];
    }
    if (n15 == 10 && q4 == 1) A2[0] = (f16)1.f;   // row10 -> 1.0 everywhere

    // ---------- conv1 via MFMA, two sub-phases of 2 images each --------------
    #pragma unroll 1
    for (int sub = 0; sub < 2; ++sub) {
        // stage x as shifted f16 pairs, row-interleaved across the 2 images.
        if (tid < 112) {
            const int rr = tid >> 2, imL = (tid >> 1) & 1, half = tid & 1;
            const int ig = min(blockIdx.x * IPB + sub * 2 + imL, batch - 1);
            const float* xp = x + (size_t)ig * 784 + rr * 28 + half * 14;
            float v[15];
            #pragma unroll
            for (int t = 0; t < 7; ++t) {
                const f32x2 a = *(const f32x2*)(xp + 2 * t);
                v[2 * t] = a[0]; v[2 * t + 1] = a[1];
            }
            v[14] = half ? 0.f : xp[14];
            uint* pw = (uint*)(smem + XH + rr * 224 + imL * 112) + half * 14;
            #pragma unroll
            for (int t = 0; t < 7; ++t) {
                uint2 w;
                w.x = __builtin_bit_cast(uint, pkrtz(v[2 * t], v[2 * t + 1]));
                w.y = __builtin_bit_cast(uint, pkrtz(v[2 * t + 1], v[2 * t + 2]));
                *(uint2*)(pw + 2 * t) = w;
            }
        } else if (sub == 0 && tid >= 224) {   // finite zero tail, written once
            *(uint*)(smem + XH + 28 * 224 + (tid - 224) * 4) = 0;
        }
        __syncthreads();

        // pool loop: wave = (imL = wv>>1, oxg = wv&1); u = 11..0 fully
        // unrolled -> every LDS address is base + compile-time immediate.
        // B2 rows (2u+4, 2u+5) = quad0's B1 rows of iteration u+2 -> 2-deep
        // named-register history (u=11,10 read direct).
        {
            const int imL = wv_ >> 1, oxg = wv_ & 1;
            const int ox = oxg * 16 + n15;
            const int im = sub * 2 + imL;
            const unsigned char* pb = smem + XH + imL * 112 + ox * 4
                                    + q4 * 224;           // + row offset base
            unsigned char* wbase = smem + im * P1I;
            f16x8 hA0 = {}, hB0 = {}, hA1 = {}, hB1 = {};
            #pragma unroll
            for (int uu = 0; uu < 12; ++uu) {
                const int u = 11 - uu;
                const f16x8 B1a = ldpairs(pb + (2 * u) * 224);
                const f16x8 B1b = ldpairs(pb + (2 * u + 1) * 224);
                f16x8 B2a, B2b;
                if (u >= 10) {   // compile-time branch
                    B2a = ldpairs(pb - q4 * 224 + (2 * u + 4) * 224);
                    B2b = ldpairs(pb - q4 * 224 + (2 * u + 5) * 224);
                } else {
                    B2a = (u & 1) ? hA1 : hA0;
                    B2b = (u & 1) ? hB1 : hB0;
                }
                if (u & 1) { hA1 = B1a; hB1 = B1b; }
                else       { hA0 = B1a; hB0 = B1b; }
                if (q4 == 1) { B2a[0] = (f16)1.f; B2b[0] = (f16)1.f; } // bias
                f32x4 aa = {0.f, 0.f, 0.f, 0.f}, ab = {0.f, 0.f, 0.f, 0.f};
                aa = __builtin_amdgcn_mfma_f32_16x16x32_f16(A1, B1a, aa, 0, 0, 0);
                ab = __builtin_amdgcn_mfma_f32_16x16x32_f16(A1, B1b, ab, 0, 0, 0);
                aa = __builtin_amdgcn_mfma_f32_16x16x32_f16(A2, B2a, aa, 0, 0, 0);
                ab = __builtin_amdgcn_mfma_f32_16x16x32_f16(A2, B2b, ab, 0, 0, 0);
                // pool (rows in-register, cols via DPP xor1) + relu
                float vr[4];
                #pragma unroll
                for (int r = 0; r < 4; ++r) {
                    float v = fmaxf(aa[r], ab[r]);
                    v = dppmax<0xB1>(v);               // lane n <-> n^1
                    vr[r] = fmaxf(v, 0.f);
                }
                if (!(lane & 1) && q4 < 3 && (oxg == 0 || n15 < 8)) {
                    const int px = oxg * 8 + (n15 >> 1);
                    f16x2 o0, o1;
                    o0[0] = (f16)vr[0]; o0[1] = (f16)vr[1];
                    o1[0] = (f16)vr[2]; o1[1] = (f16)vr[3];
                    uint2 w;
                    w.x = __builtin_bit_cast(uint, o0);
                    w.y = __builtin_bit_cast(uint, o1);
                    // XOR-swizzled in-row offset (key = u&3, compile-time)
                    const int Cw = (px * P1C + q4 * 8) ^ ((u & 3) << 3);
                    *(uint2*)(wbase + u * P1R + Cw) = w;
                }
            }
        }
        __syncthreads();
    }

    // ---------- conv2 via mfma_f32_32x32x16_f16 (2 tiles/wave) ---------------
    {
        const int cy = cM >> 3, cx = cM & 7;
        const int afoff = (cM < 20 ? cM : 19) * 2 + hK;
        int rowb[2];
        #pragma unroll
        for (int q = 0; q < 2; ++q) {
            const int t = wv_ * 2 + q, im = t >> 1, h2 = t & 1;
            rowb[q] = im * P1I + (4 * h2 + cy) * P1R;
        }
        const int Cb = cx * P1C + hK * 16;   // in-row byte offset (per-lane)
        f32x16 acc[2];
        #pragma unroll
        for (int q = 0; q < 2; ++q)
            #pragma unroll
            for (int r = 0; r < 16; ++r) acc[q][r] = 0.f;
        #pragma unroll 1
        for (int ky = 0; ky < 5; ++ky) {
            const int Kk = ((cy + ky) & 3) << 3;   // row&3 key (4h2 == 0 mod 4)
            #pragma unroll
            for (int kx = 0; kx < 5; ++kx) {
                const f16x8 a = w2af[(ky * 5 + kx) * 40 + afoff];
                const int Clo = (Cb + kx * P1C) ^ Kk;
                const int Chi = (Cb + kx * P1C + 8) ^ Kk;
                #pragma unroll
                for (int q = 0; q < 2; ++q) {
                    const unsigned char* rp = smem + rowb[q] + ky * P1R;
                    const f16x4 lo = *(const f16x4*)(rp + Clo);
                    const f16x4 hi = *(const f16x4*)(rp + Chi); // ic12-15 junk x 0
                    f16x8 b;
                    #pragma unroll
                    for (int j = 0; j < 4; ++j) { b[j] = lo[j]; b[4 + j] = hi[j]; }
                    acc[q] = __builtin_amdgcn_mfma_f32_32x32x16_f16(a, b, acc[q],
                                                                    0, 0, 0);
                }
            }
        }
        // all waves done READING p1 before epilogue overwrites it (p2h alias)
        __syncthreads();
        // epilogue: pool via DPP (bias already inside acc), aligned f16x4 store
        #pragma unroll
        for (int q = 0; q < 2; ++q) {
            const int t = wv_ * 2 + q, im = t >> 1, h2 = t & 1;
            const int py = 2 * h2 + (cM >> 4), px = (cM & 7) >> 1;
            f16* base = p2h + im * 328 + (py * 4 + px) * 20 + 4 * hK;
            #pragma unroll
            for (int g = 0; g < 4; ++g) {
                const int m0 = 8 * g + 4 * hK;       // run start channel
                f16x4 vv;
                #pragma unroll
                for (int e = 0; e < 4; ++e) {
                    float v = acc[q][4 * g + e];
                    v = dppmax<0xB1>(v);    // xor1: quad_perm(1,0,3,2)
                    v = dppmax<0x128>(v);   // xor8: row_ror:8
                    vv[e] = (f16)fmaxf(v, 0.f);
                }
                if ((lane & 9) == 0 && m0 < 20)
                    *(f16x4*)(base + 8 * g) = vv;
            }
        }
    }
    __syncthreads();

    // ---------- fc1 via mfma_f32_16x16x32_f16: M=h tile/wave, N=img, K=320 ----
    {
        f32x4 facc = {0.f, 0.f, 0.f, 0.f};
        #pragma unroll 1
        for (int s = 0; s < 10; ++s) {
            const f16x8 a = wl1pk[(wv_ * 10 + s) * 64 + lane];  // coalesced b128
            f16x8 b = {};
            if (n15 < IPB)
                b = *(const f16x8*)(p2h + n15 * 328 + s * 32 + q4 * 8);
            facc = __builtin_amdgcn_mfma_f32_16x16x32_f16(a, b, facc, 0, 0, 0);
        }
        if (n15 < IPB) {
            #pragma unroll
            for (int r = 0; r < 4; ++r) {
                const int h = wv_ * 16 + q4 * 4 + r;
                if (h < 50)
                    h1[n15 * 52 + h] = fmaxf(facc[r] + bl1[h], 0.f);
            }
        }
    }
    __syncthreads();

    // ---------- fc2: 50->10 ---------------------------------------------------
    if (tid < IPB * 10) {
        const int im = tid / 10, o = tid % 10;
        const int imgo = min(blockIdx.x * IPB + im, batch - 1);
        float a = bl2[o];
        #pragma unroll
        for (int h = 0; h < 50; ++h)
            a += h1[im * 52 + h] * wl2[o * 50 + h];
        out[(size_t)imgo * 10 + o] = a;          // coalesced
    }
}

extern "C" void kernel_launch(void* const* d_in, const int* in_sizes, int n_in,
                              void* d_out, int out_size, void* d_ws, size_t ws_size,
                              hipStream_t stream) {
    const float* x   = (const float*)d_in[0];
    const float* w1  = (const float*)d_in[1];
    const float* b1  = (const float*)d_in[2];
    const float* w2  = (const float*)d_in[3];
    const float* b2  = (const float*)d_in[4];
    const float* wl1 = (const float*)d_in[5];
    const float* bl1 = (const float*)d_in[6];
    const float* wl2 = (const float*)d_in[7];
    const float* bl2 = (const float*)d_in[8];
    float* out = (float*)d_out;
    unsigned char* ws = (unsigned char*)d_ws;

    const int batch = in_sizes[0] / 784;  // 8192
    pack_weights<<<64, 256, 0, stream>>>(w1, w2, wl1, b2, ws);
    const int grid = (batch + IPB - 1) / IPB;
    lenet_one<<<grid, THREADS, 0, stream>>>(x, ws, w1, b1, bl1, wl2, bl2,
                                            out, batch);
}